// Round 10
// baseline (214.357 us; speedup 1.0000x reference)
//
#include <hip/hip_runtime.h>
#include <hip/hip_bf16.h>

typedef float f32x4 __attribute__((ext_vector_type(4)));
typedef short s16x8 __attribute__((ext_vector_type(8)));

#define B_ 4
#define S_ 2048
#define D_ 768

typedef const __attribute__((address_space(1))) char* gas_t;
typedef __attribute__((address_space(3))) char* las_t;

__device__ __forceinline__ void gload_lds16(const void* g, void* l) {
  __builtin_amdgcn_global_load_lds((gas_t)g, (las_t)l, 16, 0, 0);
}

// ---------------- f32 -> bf16 conversion ----------------
__global__ void cvt_kernel(const float* __restrict__ x,
                           const float* __restrict__ wq,
                           const float* __restrict__ wk,
                           const float* __restrict__ wv,
                           __hip_bfloat16* __restrict__ xb,
                           __hip_bfloat16* __restrict__ wqb,
                           __hip_bfloat16* __restrict__ wkb,
                           __hip_bfloat16* __restrict__ wvb) {
  const int NX = B_ * S_ * D_ / 4;
  const int NW = D_ * D_ / 4;
  int stride = gridDim.x * blockDim.x;
  for (int j = blockIdx.x * blockDim.x + threadIdx.x; j < NX + 3 * NW; j += stride) {
    const float4* src; __hip_bfloat16* dst; int off;
    if (j < NX)             { src = (const float4*)x;  dst = xb;  off = j; }
    else if (j < NX + NW)   { src = (const float4*)wq; dst = wqb; off = j - NX; }
    else if (j < NX + 2*NW) { src = (const float4*)wk; dst = wkb; off = j - NX - NW; }
    else                    { src = (const float4*)wv; dst = wvb; off = j - NX - 2*NW; }
    float4 v = src[off];
    dst[4*off+0] = __float2bfloat16(v.x);
    dst[4*off+1] = __float2bfloat16(v.y);
    dst[4*off+2] = __float2bfloat16(v.z);
    dst[4*off+3] = __float2bfloat16(v.w);
  }
}

// ---- 128-row staging (4-wave kernels), source pre-swizzled ----
__device__ __forceinline__ void stage_tile64(const __hip_bfloat16* __restrict__ base,
                                             size_t stride, int r0, int k0,
                                             char* lds, int w, int l) {
#pragma unroll
  for (int it = 0; it < 4; ++it) {
    int ra = it * 32 + w * 8 + (l >> 3);
    int slot = (l & 7) ^ ((l >> 3) & 7);
    gload_lds16(base + (size_t)(r0 + ra) * stride + k0 + slot * 8,
                lds + it * 4096 + w * 1024);
  }
}

// ---- 256-row staging (8-wave kernel), source pre-swizzled ----
__device__ __forceinline__ void stage_tile256(const __hip_bfloat16* __restrict__ base,
                                              size_t stride, int r0, int k0,
                                              char* lds, int w, int l) {
#pragma unroll
  for (int it = 0; it < 4; ++it) {
    int row = it * 64 + w * 8 + (l >> 3);
    int slot = (l & 7) ^ ((l >> 3) & 7);
    gload_lds16(base + (size_t)(r0 + row) * stride + k0 + slot * 8,
                lds + it * 8192 + w * 1024);
  }
}

// swizzled fragment read: element index for logical (row R, slot s)
#define SWZ_IDX(R, s) ((R) * 64 + (((s) ^ ((R) & 7)) * 8))

// ---------------- QKV projection GEMM: 256x256 tile, 8 waves, counted vmcnt ----------------
// z=0: Q = x @ Wq^T ; z=1: K = x @ Wk^T ; z=2: Vt = Wv @ x^T (V transposed [B][768][2048])
__launch_bounds__(512, 1)
__global__ void qkv_gemm256(const __hip_bfloat16* __restrict__ xb,
                            const __hip_bfloat16* __restrict__ wqb,
                            const __hip_bfloat16* __restrict__ wkb,
                            const __hip_bfloat16* __restrict__ wvb,
                            __hip_bfloat16* __restrict__ Qb,
                            __hip_bfloat16* __restrict__ Kb,
                            __hip_bfloat16* __restrict__ Vt) {
  __shared__ __hip_bfloat16 At[2][256 * 64];   // 64 KB
  __shared__ __hip_bfloat16 Bt[2][256 * 64];   // 64 KB
  const int z = blockIdx.z;
  const __hip_bfloat16* Ag;
  const __hip_bfloat16* Bg;
  int m0, n0;
  if (z == 0)      { Ag = xb;  Bg = wqb; m0 = blockIdx.x * 256; n0 = blockIdx.y * 256; }
  else if (z == 1) { Ag = xb;  Bg = wkb; m0 = blockIdx.x * 256; n0 = blockIdx.y * 256; }
  else             { Ag = wvb; Bg = xb;  m0 = blockIdx.y * 256; n0 = blockIdx.x * 256; }

  const int tid = threadIdx.x, w = tid >> 6, l = tid & 63;
  const int wm = w >> 2, wn = w & 3;   // 2 x 4 wave grid; wave owns 128x64 output
  f32x4 acc[8][4] = {};

  stage_tile256(Ag, 768, m0, 0, (char*)At[0], w, l);
  stage_tile256(Bg, 768, n0, 0, (char*)Bt[0], w, l);

  const int NT = 12;  // K=768 / BK=64
  for (int t = 0; t < NT; ++t) {
    // B1: all waves finished reading buf[(t-1)&1]; stage writes may now target it
    __builtin_amdgcn_sched_barrier(0);
    asm volatile("s_waitcnt lgkmcnt(0)" ::: "memory");
    __builtin_amdgcn_s_barrier();
    __builtin_amdgcn_sched_barrier(0);
    if (t + 1 < NT) {
      stage_tile256(Ag, 768, m0, (t + 1) * 64, (char*)At[(t + 1) & 1], w, l);
      stage_tile256(Bg, 768, n0, (t + 1) * 64, (char*)Bt[(t + 1) & 1], w, l);
      asm volatile("s_waitcnt vmcnt(8)" ::: "memory");  // tile t's 8 loads landed
    } else {
      asm volatile("s_waitcnt vmcnt(0)" ::: "memory");
    }
    __builtin_amdgcn_s_barrier();  // B2: every wave's tile-t stages landed
    __builtin_amdgcn_sched_barrier(0);
    const __hip_bfloat16* Ab = At[t & 1];
    const __hip_bfloat16* Bb = Bt[t & 1];
#pragma unroll
    for (int kk = 0; kk < 2; ++kk) {
      s16x8 a[8], bfr[4];
      int s = kk * 4 + (l >> 4);
#pragma unroll
      for (int mf = 0; mf < 8; ++mf) {
        int R = wm * 128 + mf * 16 + (l & 15);
        a[mf] = *(const s16x8*)&Ab[SWZ_IDX(R, s)];
      }
#pragma unroll
      for (int nf = 0; nf < 4; ++nf) {
        int R = wn * 64 + nf * 16 + (l & 15);
        bfr[nf] = *(const s16x8*)&Bb[SWZ_IDX(R, s)];
      }
      __builtin_amdgcn_s_setprio(1);
#pragma unroll
      for (int mf = 0; mf < 8; ++mf)
#pragma unroll
        for (int nf = 0; nf < 4; ++nf)
          acc[mf][nf] = __builtin_amdgcn_mfma_f32_16x16x32_bf16(a[mf], bfr[nf], acc[mf][nf], 0, 0, 0);
      __builtin_amdgcn_s_setprio(0);
    }
  }

  if (z < 2) {
    __hip_bfloat16* outp = (z == 0) ? Qb : Kb;
#pragma unroll
    for (int mf = 0; mf < 8; ++mf) {
      int m = m0 + wm * 128 + mf * 16 + (l >> 4) * 4;
#pragma unroll
      for (int nf = 0; nf < 4; ++nf) {
        int n = n0 + wn * 64 + nf * 16 + (l & 15);
#pragma unroll
        for (int r = 0; r < 4; ++r)
          outp[(size_t)(m + r) * 768 + n] = __float2bfloat16(acc[mf][nf][r]);
      }
    }
  } else {
#pragma unroll
    for (int mf = 0; mf < 8; ++mf) {
      int dd = m0 + wm * 128 + mf * 16 + (l >> 4) * 4;
#pragma unroll
      for (int nf = 0; nf < 4; ++nf) {
        int sg = n0 + wn * 64 + nf * 16 + (l & 15);
        int bb = sg >> 11, sl = sg & 2047;
#pragma unroll
        for (int r = 0; r < 4; ++r)
          Vt[(size_t)bb * D_ * S_ + (size_t)(dd + r) * S_ + sl] = __float2bfloat16(acc[mf][nf][r]);
      }
    }
  }
}

// ---------------- S = scale*log2e * Q K^T, causal-masked, bf16 (128², 2-phase) ----------------
__launch_bounds__(256, 2)
__global__ void qk_gemm(const __hip_bfloat16* __restrict__ Qb,
                        const __hip_bfloat16* __restrict__ Kb,
                        __hip_bfloat16* __restrict__ Sb) {
  __shared__ __hip_bfloat16 At[2][128 * 64];
  __shared__ __hip_bfloat16 Bt[2][128 * 64];
  const int qt = blockIdx.x, kt = blockIdx.y, b = blockIdx.z;
  if (kt > qt) return;
  const int m0 = qt * 128, n0 = kt * 128;
  const __hip_bfloat16* Ag = Qb + (size_t)b * S_ * D_;
  const __hip_bfloat16* Bg = Kb + (size_t)b * S_ * D_;
  const int tid = threadIdx.x, w = tid >> 6, l = tid & 63;
  const int wr = w >> 1, wc = w & 1;
  const float SC = 0.03608439182435161f * 1.4426950408889634f;
  f32x4 acc[4][4] = {};

  stage_tile64(Ag, D_, m0, 0, (char*)At[0], w, l);
  stage_tile64(Bg, D_, n0, 0, (char*)Bt[0], w, l);
  int cur = 0;
  for (int k0 = 0; k0 < D_; k0 += 64) {
    __syncthreads();
    if (k0 + 64 < D_) {
      stage_tile64(Ag, D_, m0, k0 + 64, (char*)At[cur ^ 1], w, l);
      stage_tile64(Bg, D_, n0, k0 + 64, (char*)Bt[cur ^ 1], w, l);
    }
#pragma unroll
    for (int kk = 0; kk < 2; ++kk) {
      s16x8 a[4], bfr[4];
      int s = kk * 4 + (l >> 4);
#pragma unroll
      for (int i = 0; i < 4; ++i) {
        int Ra = wr * 64 + i * 16 + (l & 15);
        int Rb = wc * 64 + i * 16 + (l & 15);
        a[i]   = *(const s16x8*)&At[cur][SWZ_IDX(Ra, s)];
        bfr[i] = *(const s16x8*)&Bt[cur][SWZ_IDX(Rb, s)];
      }
#pragma unroll
      for (int i = 0; i < 4; ++i)
#pragma unroll
        for (int j = 0; j < 4; ++j)
          acc[i][j] = __builtin_amdgcn_mfma_f32_16x16x32_bf16(a[i], bfr[j], acc[i][j], 0, 0, 0);
    }
    cur ^= 1;
  }

#pragma unroll
  for (int i = 0; i < 4; ++i) {
    int m = m0 + wr * 64 + i * 16 + (l >> 4) * 4;
#pragma unroll
    for (int j = 0; j < 4; ++j) {
      int n = n0 + wc * 64 + j * 16 + (l & 15);
#pragma unroll
      for (int r = 0; r < 4; ++r) {
        float zz = (n > m + r) ? -1e30f : acc[i][j][r] * SC;
        Sb[(size_t)(b * S_ + m + r) * S_ + n] = __float2bfloat16(zz);
      }
    }
  }
}

// ---------------- row softmax: P = exp2(S - m)/sum, bf16 ----------------
__launch_bounds__(256, 4)
__global__ void softmax_kernel(const __hip_bfloat16* __restrict__ Sb,
                               __hip_bfloat16* __restrict__ Pb) {
  const int tid = threadIdx.x, w = tid >> 6, l = tid & 63;
  const int r = blockIdx.x * 4 + w;
  const int q = r & (S_ - 1);
  const int L = ((q >> 7) + 1) << 7;
  const ushort* srow = (const ushort*)(Sb + (size_t)r * S_);
  ushort* prow = (ushort*)(Pb + (size_t)r * S_);
  f32x4 ch[8];
#pragma unroll
  for (int it = 0; it < 8; ++it) {
    int idx = it * 256 + l * 4;
    if (idx < L) {
      ushort4 u = *(const ushort4*)&srow[idx];
      ch[it].x = __uint_as_float((unsigned)u.x << 16);
      ch[it].y = __uint_as_float((unsigned)u.y << 16);
      ch[it].z = __uint_as_float((unsigned)u.z << 16);
      ch[it].w = __uint_as_float((unsigned)u.w << 16);
    } else {
      ch[it].x = -1e30f; ch[it].y = -1e30f; ch[it].z = -1e30f; ch[it].w = -1e30f;
    }
  }
  float mx = -1e30f;
#pragma unroll
  for (int it = 0; it < 8; ++it)
    mx = fmaxf(mx, fmaxf(fmaxf(ch[it].x, ch[it].y), fmaxf(ch[it].z, ch[it].w)));
#pragma unroll
  for (int d = 1; d < 64; d <<= 1) mx = fmaxf(mx, __shfl_xor(mx, d, 64));
  float sum = 0.f;
#pragma unroll
  for (int it = 0; it < 8; ++it) {
    ch[it].x = exp2f(ch[it].x - mx);
    ch[it].y = exp2f(ch[it].y - mx);
    ch[it].z = exp2f(ch[it].z - mx);
    ch[it].w = exp2f(ch[it].w - mx);
    sum += (ch[it].x + ch[it].y) + (ch[it].z + ch[it].w);
  }
#pragma unroll
  for (int d = 1; d < 64; d <<= 1) sum += __shfl_xor(sum, d, 64);
  const float rinv = 1.0f / sum;
#pragma unroll
  for (int it = 0; it < 8; ++it) {
    int idx = it * 256 + l * 4;
    if (idx < L) {
      __hip_bfloat16 h0 = __float2bfloat16(ch[it].x * rinv);
      __hip_bfloat16 h1 = __float2bfloat16(ch[it].y * rinv);
      __hip_bfloat16 h2 = __float2bfloat16(ch[it].z * rinv);
      __hip_bfloat16 h3 = __float2bfloat16(ch[it].w * rinv);
      ushort4 u;
      u.x = *(ushort*)&h0; u.y = *(ushort*)&h1; u.z = *(ushort*)&h2; u.w = *(ushort*)&h3;
      *(ushort4*)&prow[idx] = u;
    }
  }
}

// ---------------- O = P V with split-K for long rows ----------------
// blockIdx.x in 0..23 (reversed -> long K first):
//   xx <  8 : qt = xx      (K = (qt+1)*128 <= 1024), write f32 directly to out
//   xx >= 8 : qt = 8+(xx-8)/2, half = (xx-8)&1, K-half = (qt+1)*64 -> part0/part1
__launch_bounds__(256, 2)
__global__ void pv_gemm(const __hip_bfloat16* __restrict__ Pb,
                        const __hip_bfloat16* __restrict__ Vt,
                        float* __restrict__ out,
                        float* __restrict__ part0,
                        float* __restrict__ part1) {
  __shared__ __hip_bfloat16 At[2][128 * 64];
  __shared__ __hip_bfloat16 Bt[2][128 * 64];
  const int xx = 23 - (int)blockIdx.x, dt = blockIdx.y, b = blockIdx.z;
  int qt, klo, khi;
  float* dst; int mbase;
  if (xx < 8) {
    qt = xx; klo = 0; khi = (qt + 1) * 128;
    dst = out + (size_t)b * S_ * D_; mbase = qt * 128;
  } else {
    int idx = xx - 8;
    qt = 8 + (idx >> 1);
    int half = idx & 1, kh = (qt + 1) * 64;
    klo = half * kh; khi = klo + kh;
    dst = (half ? part1 : part0) + (size_t)b * 1024 * D_;
    mbase = qt * 128 - 1024;  // rows 1024..2047 -> part rows 0..1023
  }
  const int m0 = qt * 128, n0 = dt * 128;
  const __hip_bfloat16* Ag = Pb + (size_t)b * S_ * S_;
  const __hip_bfloat16* Bg = Vt + (size_t)b * D_ * S_;
  const int tid = threadIdx.x, w = tid >> 6, l = tid & 63;
  const int wr = w >> 1, wc = w & 1;
  f32x4 acc[4][4] = {};

  stage_tile64(Ag, S_, m0, klo, (char*)At[0], w, l);
  stage_tile64(Bg, S_, n0, klo, (char*)Bt[0], w, l);
  int cur = 0;
  for (int k0 = klo; k0 < khi; k0 += 64) {
    __syncthreads();
    if (k0 + 64 < khi) {
      stage_tile64(Ag, S_, m0, k0 + 64, (char*)At[cur ^ 1], w, l);
      stage_tile64(Bg, S_, n0, k0 + 64, (char*)Bt[cur ^ 1], w, l);
    }
#pragma unroll
    for (int kk = 0; kk < 2; ++kk) {
      s16x8 a[4], bfr[4];
      int s = kk * 4 + (l >> 4);
#pragma unroll
      for (int i = 0; i < 4; ++i) {
        int Ra = wr * 64 + i * 16 + (l & 15);
        int Rb = wc * 64 + i * 16 + (l & 15);
        a[i]   = *(const s16x8*)&At[cur][SWZ_IDX(Ra, s)];
        bfr[i] = *(const s16x8*)&Bt[cur][SWZ_IDX(Rb, s)];
      }
#pragma unroll
      for (int i = 0; i < 4; ++i)
#pragma unroll
        for (int j = 0; j < 4; ++j)
          acc[i][j] = __builtin_amdgcn_mfma_f32_16x16x32_bf16(a[i], bfr[j], acc[i][j], 0, 0, 0);
    }
    cur ^= 1;
  }

#pragma unroll
  for (int i = 0; i < 4; ++i) {
    int m = mbase + wr * 64 + i * 16 + (l >> 4) * 4;
#pragma unroll
    for (int j = 0; j < 4; ++j) {
      int n = n0 + wc * 64 + j * 16 + (l & 15);
#pragma unroll
      for (int r = 0; r < 4; ++r)
        dst[(size_t)(m + r) * D_ + n] = acc[i][j][r];
    }
  }
}

// ---------------- combine: out rows 1024..2047 = part0 + part1 ----------------
__global__ void combine_kernel(const float* __restrict__ part0,
                               const float* __restrict__ part1,
                               float* __restrict__ out) {
  const int N4 = B_ * 1024 * D_ / 4;  // 786432 float4
  const float4* p0 = (const float4*)part0;
  const float4* p1 = (const float4*)part1;
  float4* o = (float4*)out;
  int stride = gridDim.x * blockDim.x;
  for (int f = blockIdx.x * blockDim.x + threadIdx.x; f < N4; f += stride) {
    int b = f / (1024 * D_ / 4);
    int oidx = f % (1024 * D_ / 4);
    float4 a = p0[f], c = p1[f];
    float4 v = make_float4(a.x + c.x, a.y + c.y, a.z + c.z, a.w + c.w);
    o[(size_t)b * S_ * D_ / 4 + (size_t)1024 * D_ / 4 + oidx] = v;
  }
}

extern "C" void kernel_launch(void* const* d_in, const int* in_sizes, int n_in,
                              void* d_out, int out_size, void* d_ws, size_t ws_size,
                              hipStream_t stream) {
  const float* x  = (const float*)d_in[0];
  const float* wq = (const float*)d_in[1];
  const float* wk = (const float*)d_in[2];
  const float* wv = (const float*)d_in[3];
  char* ws = (char*)d_ws;
  // layout: xb 0..12.58M | w* ..16.12M | Qb ..28.70M | Kb ..41.29M | Vt ..53.87M
  //         Sb 53.87M..87.43M | Pb 0..33.55M (reuses dead region)
  //         part0/part1 53.87M..79.04M (reuse dead Sb during pv)
  __hip_bfloat16* xb  = (__hip_bfloat16*)(ws + 0);
  __hip_bfloat16* wqb = (__hip_bfloat16*)(ws + 12582912);
  __hip_bfloat16* wkb = (__hip_bfloat16*)(ws + 12582912 + 1179648);
  __hip_bfloat16* wvb = (__hip_bfloat16*)(ws + 12582912 + 2 * 1179648);
  __hip_bfloat16* Qb  = (__hip_bfloat16*)(ws + 16121856);
  __hip_bfloat16* Kb  = (__hip_bfloat16*)(ws + 28704768);
  __hip_bfloat16* Vt  = (__hip_bfloat16*)(ws + 41287680);
  __hip_bfloat16* Sb  = (__hip_bfloat16*)(ws + 53870592);
  __hip_bfloat16* Pb  = (__hip_bfloat16*)(ws + 0);
  float* part0 = (float*)(ws + 53870592);
  float* part1 = (float*)(ws + 53870592 + 12582912);

  cvt_kernel<<<2048, 256, 0, stream>>>(x, wq, wk, wv, xb, wqb, wkb, wvb);
  qkv_gemm256<<<dim3(32, 3, 3), 512, 0, stream>>>(xb, wqb, wkb, wvb, Qb, Kb, Vt);
  qk_gemm<<<dim3(16, 16, 4), 256, 0, stream>>>(Qb, Kb, Sb);
  softmax_kernel<<<2048, 256, 0, stream>>>(Sb, Pb);
  pv_gemm<<<dim3(24, 6, 4), 256, 0, stream>>>(Pb, Vt, (float*)d_out, part0, part1);
  combine_kernel<<<1024, 256, 0, stream>>>(part0, part1, (float*)d_out);
}

// Round 11
// 206.010 us; speedup vs baseline: 1.0405x; 1.0405x over previous
//
#include <hip/hip_runtime.h>
#include <hip/hip_bf16.h>

typedef float f32x4 __attribute__((ext_vector_type(4)));
typedef short s16x8 __attribute__((ext_vector_type(8)));

#define B_ 4
#define S_ 2048
#define D_ 768

typedef const __attribute__((address_space(1))) char* gas_t;
typedef __attribute__((address_space(3))) char* las_t;

__device__ __forceinline__ void gload_lds16(const void* g, void* l) {
  __builtin_amdgcn_global_load_lds((gas_t)g, (las_t)l, 16, 0, 0);
}

// ---------------- f32 -> bf16 conversion ----------------
__global__ void cvt_kernel(const float* __restrict__ x,
                           const float* __restrict__ wq,
                           const float* __restrict__ wk,
                           const float* __restrict__ wv,
                           __hip_bfloat16* __restrict__ xb,
                           __hip_bfloat16* __restrict__ wqb,
                           __hip_bfloat16* __restrict__ wkb,
                           __hip_bfloat16* __restrict__ wvb) {
  const int NX = B_ * S_ * D_ / 4;
  const int NW = D_ * D_ / 4;
  int stride = gridDim.x * blockDim.x;
  for (int j = blockIdx.x * blockDim.x + threadIdx.x; j < NX + 3 * NW; j += stride) {
    const float4* src; __hip_bfloat16* dst; int off;
    if (j < NX)             { src = (const float4*)x;  dst = xb;  off = j; }
    else if (j < NX + NW)   { src = (const float4*)wq; dst = wqb; off = j - NX; }
    else if (j < NX + 2*NW) { src = (const float4*)wk; dst = wkb; off = j - NX - NW; }
    else                    { src = (const float4*)wv; dst = wvb; off = j - NX - 2*NW; }
    float4 v = src[off];
    dst[4*off+0] = __float2bfloat16(v.x);
    dst[4*off+1] = __float2bfloat16(v.y);
    dst[4*off+2] = __float2bfloat16(v.z);
    dst[4*off+3] = __float2bfloat16(v.w);
  }
}

// ---- 128-row staging, source pre-swizzled (rule #21) ----
__device__ __forceinline__ void stage_tile64(const __hip_bfloat16* __restrict__ base,
                                             size_t stride, int r0, int k0,
                                             char* lds, int w, int l) {
#pragma unroll
  for (int it = 0; it < 4; ++it) {
    int ra = it * 32 + w * 8 + (l >> 3);
    int slot = (l & 7) ^ ((l >> 3) & 7);
    gload_lds16(base + (size_t)(r0 + ra) * stride + k0 + slot * 8,
                lds + it * 4096 + w * 1024);
  }
}

// swizzled fragment read: element index for logical (row R, slot s)
#define SWZ_IDX(R, s) ((R) * 64 + (((s) ^ ((R) & 7)) * 8))

// ---------------- QKV projection GEMM (r9 version: 128², BK=64, 2-phase, swizzle) ----
__launch_bounds__(256, 2)
__global__ void qkv_gemm(const __hip_bfloat16* __restrict__ xb,
                         const __hip_bfloat16* __restrict__ wqb,
                         const __hip_bfloat16* __restrict__ wkb,
                         const __hip_bfloat16* __restrict__ wvb,
                         __hip_bfloat16* __restrict__ Qb,
                         __hip_bfloat16* __restrict__ Kb,
                         __hip_bfloat16* __restrict__ Vt) {
  __shared__ __hip_bfloat16 At[2][128 * 64];
  __shared__ __hip_bfloat16 Bt[2][128 * 64];
  const int z = blockIdx.z;
  const __hip_bfloat16* Ag;
  const __hip_bfloat16* Bg;
  int m0, n0;
  if (z == 0)      { Ag = xb;  Bg = wqb; m0 = blockIdx.x * 128; n0 = blockIdx.y * 128; }
  else if (z == 1) { Ag = xb;  Bg = wkb; m0 = blockIdx.x * 128; n0 = blockIdx.y * 128; }
  else             { Ag = wvb; Bg = xb;  m0 = blockIdx.y * 128; n0 = blockIdx.x * 128; }

  const int tid = threadIdx.x, w = tid >> 6, l = tid & 63;
  const int wr = w >> 1, wc = w & 1;
  f32x4 acc[4][4] = {};

  stage_tile64(Ag, 768, m0, 0, (char*)At[0], w, l);
  stage_tile64(Bg, 768, n0, 0, (char*)Bt[0], w, l);
  int cur = 0;
  for (int k0 = 0; k0 < 768; k0 += 64) {
    __syncthreads();
    if (k0 + 64 < 768) {
      stage_tile64(Ag, 768, m0, k0 + 64, (char*)At[cur ^ 1], w, l);
      stage_tile64(Bg, 768, n0, k0 + 64, (char*)Bt[cur ^ 1], w, l);
    }
#pragma unroll
    for (int kk = 0; kk < 2; ++kk) {
      s16x8 a[4], b[4];
      int s = kk * 4 + (l >> 4);
#pragma unroll
      for (int i = 0; i < 4; ++i) {
        int Ra = wr * 64 + i * 16 + (l & 15);
        int Rb = wc * 64 + i * 16 + (l & 15);
        a[i] = *(const s16x8*)&At[cur][SWZ_IDX(Ra, s)];
        b[i] = *(const s16x8*)&Bt[cur][SWZ_IDX(Rb, s)];
      }
#pragma unroll
      for (int i = 0; i < 4; ++i)
#pragma unroll
        for (int j = 0; j < 4; ++j)
          acc[i][j] = __builtin_amdgcn_mfma_f32_16x16x32_bf16(a[i], b[j], acc[i][j], 0, 0, 0);
    }
    cur ^= 1;
  }

  if (z < 2) {
    __hip_bfloat16* outp = (z == 0) ? Qb : Kb;
#pragma unroll
    for (int i = 0; i < 4; ++i) {
      int m = m0 + wr * 64 + i * 16 + (l >> 4) * 4;
#pragma unroll
      for (int j = 0; j < 4; ++j) {
        int n = n0 + wc * 64 + j * 16 + (l & 15);
#pragma unroll
        for (int r = 0; r < 4; ++r)
          outp[(size_t)(m + r) * 768 + n] = __float2bfloat16(acc[i][j][r]);
      }
    }
  } else {
#pragma unroll
    for (int i = 0; i < 4; ++i) {
      int dd = m0 + wr * 64 + i * 16 + (l >> 4) * 4;
#pragma unroll
      for (int j = 0; j < 4; ++j) {
        int sg = n0 + wc * 64 + j * 16 + (l & 15);
        int bb = sg >> 11, sl = sg & 2047;
#pragma unroll
        for (int r = 0; r < 4; ++r)
          Vt[(size_t)bb * D_ * S_ + (size_t)(dd + r) * S_ + sl] = __float2bfloat16(acc[i][j][r]);
      }
    }
  }
}

// ---------------- P = exp2(scale*log2e * QK^T) causal (no max-sub; |score|<=9.2) ----
// Writes P bf16 + race-free per-(block,wc) 64-col row partial sums:
// RS[b][qt][kt][wc][128]  (1 MB, in dead xb region)
__launch_bounds__(256, 2)
__global__ void qk_gemm(const __hip_bfloat16* __restrict__ Qb,
                        const __hip_bfloat16* __restrict__ Kb,
                        __hip_bfloat16* __restrict__ Pb,
                        float* __restrict__ RS) {
  __shared__ __hip_bfloat16 At[2][128 * 64];
  __shared__ __hip_bfloat16 Bt[2][128 * 64];
  const int qt = blockIdx.x, kt = blockIdx.y, b = blockIdx.z;
  if (kt > qt) return;
  const int m0 = qt * 128, n0 = kt * 128;
  const __hip_bfloat16* Ag = Qb + (size_t)b * S_ * D_;
  const __hip_bfloat16* Bg = Kb + (size_t)b * S_ * D_;
  const int tid = threadIdx.x, w = tid >> 6, l = tid & 63;
  const int wr = w >> 1, wc = w & 1;
  const float SC = 0.03608439182435161f * 1.4426950408889634f;
  f32x4 acc[4][4] = {};

  stage_tile64(Ag, D_, m0, 0, (char*)At[0], w, l);
  stage_tile64(Bg, D_, n0, 0, (char*)Bt[0], w, l);
  int cur = 0;
  for (int k0 = 0; k0 < D_; k0 += 64) {
    __syncthreads();
    if (k0 + 64 < D_) {
      stage_tile64(Ag, D_, m0, k0 + 64, (char*)At[cur ^ 1], w, l);
      stage_tile64(Bg, D_, n0, k0 + 64, (char*)Bt[cur ^ 1], w, l);
    }
#pragma unroll
    for (int kk = 0; kk < 2; ++kk) {
      s16x8 a[4], bfr[4];
      int s = kk * 4 + (l >> 4);
#pragma unroll
      for (int i = 0; i < 4; ++i) {
        int Ra = wr * 64 + i * 16 + (l & 15);
        int Rb = wc * 64 + i * 16 + (l & 15);
        a[i]   = *(const s16x8*)&At[cur][SWZ_IDX(Ra, s)];
        bfr[i] = *(const s16x8*)&Bt[cur][SWZ_IDX(Rb, s)];
      }
#pragma unroll
      for (int i = 0; i < 4; ++i)
#pragma unroll
        for (int j = 0; j < 4; ++j)
          acc[i][j] = __builtin_amdgcn_mfma_f32_16x16x32_bf16(a[i], bfr[j], acc[i][j], 0, 0, 0);
    }
    cur ^= 1;
  }

  float rps[4][4];
#pragma unroll
  for (int i = 0; i < 4; ++i)
#pragma unroll
    for (int r = 0; r < 4; ++r) rps[i][r] = 0.f;

#pragma unroll
  for (int i = 0; i < 4; ++i) {
    int m = m0 + wr * 64 + i * 16 + (l >> 4) * 4;
#pragma unroll
    for (int j = 0; j < 4; ++j) {
      int n = n0 + wc * 64 + j * 16 + (l & 15);
#pragma unroll
      for (int r = 0; r < 4; ++r) {
        float p = (n > m + r) ? 0.f : exp2f(acc[i][j][r] * SC);
        __hip_bfloat16 hp = __float2bfloat16(p);
        rps[i][r] += __bfloat162float(hp);  // sum the ROUNDED p (matches PV input)
        Pb[(size_t)(b * S_ + m + r) * S_ + n] = hp;
      }
    }
  }
  // reduce over the 16 column-lanes (low 4 lane bits)
#pragma unroll
  for (int d = 1; d < 16; d <<= 1)
#pragma unroll
    for (int i = 0; i < 4; ++i)
#pragma unroll
      for (int r = 0; r < 4; ++r) rps[i][r] += __shfl_xor(rps[i][r], d, 64);
  if ((l & 15) == 0) {
    float* slice = RS + (size_t)(((b * 16 + qt) * 16 + kt) * 2 + wc) * 128;
#pragma unroll
    for (int i = 0; i < 4; ++i) {
      int row = wr * 64 + i * 16 + (l >> 4) * 4;
#pragma unroll
      for (int r = 0; r < 4; ++r) slice[row + r] = rps[i][r];
    }
  }
}

// ---------------- O = P V / rowsum, split-K (kt-aligned) for long rows ----------------
// xx<8: qt=xx, full K, normalize in-kernel. xx>=8: qt=8+(xx-8)/2, half=(xx-8)&1,
// kt-aligned halves, write unnormalized f32 parts (combine normalizes).
__launch_bounds__(256, 2)
__global__ void pv_gemm(const __hip_bfloat16* __restrict__ Pb,
                        const __hip_bfloat16* __restrict__ Vt,
                        const float* __restrict__ RS,
                        float* __restrict__ out,
                        float* __restrict__ part0,
                        float* __restrict__ part1) {
  __shared__ __hip_bfloat16 At[2][128 * 64];
  __shared__ __hip_bfloat16 Bt[2][128 * 64];
  __shared__ float Ls[128];
  const int xx = 23 - (int)blockIdx.x, dt = blockIdx.y, b = blockIdx.z;
  int qt, klo, khi, mbase;
  float* dst;
  bool direct;
  if (xx < 8) {
    qt = xx; klo = 0; khi = (qt + 1) * 128;
    dst = out + (size_t)b * S_ * D_; mbase = qt * 128; direct = true;
  } else {
    int idx = xx - 8;
    qt = 8 + (idx >> 1);
    int half = idx & 1;
    int h0 = ((qt + 2) >> 1) * 128;          // ceil((qt+1)/2) kt-tiles
    klo = half ? h0 : 0;
    khi = half ? (qt + 1) * 128 : h0;
    dst = (half ? part1 : part0) + (size_t)b * 1024 * D_;
    mbase = qt * 128 - 1024; direct = false;
  }
  const int m0 = qt * 128, n0 = dt * 128;
  const __hip_bfloat16* Ag = Pb + (size_t)b * S_ * S_;
  const __hip_bfloat16* Bg = Vt + (size_t)b * D_ * S_;
  const int tid = threadIdx.x, w = tid >> 6, l = tid & 63;
  const int wr = w >> 1, wc = w & 1;
  f32x4 acc[4][4] = {};

  if (direct && tid < 128) {
    float s = 0.f;
    const float* base = RS + (size_t)(b * 16 + qt) * 16 * 256;
    for (int kt = 0; kt <= qt; ++kt)
      s += base[kt * 256 + tid] + base[kt * 256 + 128 + tid];
    Ls[tid] = 1.0f / s;
  }

  stage_tile64(Ag, S_, m0, klo, (char*)At[0], w, l);
  stage_tile64(Bg, S_, n0, klo, (char*)Bt[0], w, l);
  int cur = 0;
  for (int k0 = klo; k0 < khi; k0 += 64) {
    __syncthreads();
    if (k0 + 64 < khi) {
      stage_tile64(Ag, S_, m0, k0 + 64, (char*)At[cur ^ 1], w, l);
      stage_tile64(Bg, S_, n0, k0 + 64, (char*)Bt[cur ^ 1], w, l);
    }
#pragma unroll
    for (int kk = 0; kk < 2; ++kk) {
      s16x8 a[4], bfr[4];
      int s = kk * 4 + (l >> 4);
#pragma unroll
      for (int i = 0; i < 4; ++i) {
        int Ra = wr * 64 + i * 16 + (l & 15);
        int Rb = wc * 64 + i * 16 + (l & 15);
        a[i]   = *(const s16x8*)&At[cur][SWZ_IDX(Ra, s)];
        bfr[i] = *(const s16x8*)&Bt[cur][SWZ_IDX(Rb, s)];
      }
#pragma unroll
      for (int i = 0; i < 4; ++i)
#pragma unroll
        for (int j = 0; j < 4; ++j)
          acc[i][j] = __builtin_amdgcn_mfma_f32_16x16x32_bf16(a[i], bfr[j], acc[i][j], 0, 0, 0);
    }
    cur ^= 1;
  }

#pragma unroll
  for (int i = 0; i < 4; ++i) {
    int lr = wr * 64 + i * 16 + (l >> 4) * 4;
    int m = mbase + lr;
#pragma unroll
    for (int j = 0; j < 4; ++j) {
      int n = n0 + wc * 64 + j * 16 + (l & 15);
#pragma unroll
      for (int r = 0; r < 4; ++r) {
        float v = acc[i][j][r];
        if (direct) v *= Ls[lr + r];
        dst[(size_t)(m + r) * D_ + n] = v;
      }
    }
  }
}

// ---------------- combine: out rows 1024..2047 = (part0+part1)/rowsum ----------------
__launch_bounds__(256, 4)
__global__ void combine_kernel(const float* __restrict__ part0,
                               const float* __restrict__ part1,
                               const float* __restrict__ RS,
                               float* __restrict__ out) {
  __shared__ float Ls[32];
  const int rg = blockIdx.x, b = blockIdx.y;   // 32 rows per block
  const int q0 = 1024 + rg * 32;
  const int tid = threadIdx.x;
  if (tid < 32) {
    int q = q0 + tid, qt = q >> 7, row = q & 127;
    float s = 0.f;
    const float* base = RS + (size_t)(b * 16 + qt) * 16 * 256;
    for (int kt = 0; kt <= qt; ++kt)
      s += base[kt * 256 + row] + base[kt * 256 + 128 + row];
    Ls[tid] = 1.0f / s;
  }
  __syncthreads();
  const int F = 32 * (D_ / 4);  // 6144 float4 per block
  const float4* p0 = (const float4*)(part0 + (size_t)b * 1024 * D_);
  const float4* p1 = (const float4*)(part1 + (size_t)b * 1024 * D_);
  float4* o = (float4*)(out + (size_t)b * S_ * D_);
  for (int f = tid; f < F; f += 256) {
    int r = f / (D_ / 4), c = f % (D_ / 4);
    int prow = (q0 - 1024) + r;
    float4 a = p0[(size_t)prow * (D_ / 4) + c];
    float4 d = p1[(size_t)prow * (D_ / 4) + c];
    float sc = Ls[r];
    float4 v = make_float4((a.x + d.x) * sc, (a.y + d.y) * sc,
                           (a.z + d.z) * sc, (a.w + d.w) * sc);
    o[(size_t)(q0 + r) * (D_ / 4) + c] = v;
  }
}

extern "C" void kernel_launch(void* const* d_in, const int* in_sizes, int n_in,
                              void* d_out, int out_size, void* d_ws, size_t ws_size,
                              hipStream_t stream) {
  const float* x  = (const float*)d_in[0];
  const float* wq = (const float*)d_in[1];
  const float* wk = (const float*)d_in[2];
  const float* wv = (const float*)d_in[3];
  char* ws = (char*)d_ws;
  // layout: xb 0..12.58M | w* ..16.12M | Qb ..28.70M | Kb ..41.29M | Vt ..53.87M
  //         Pb 53.87M..87.43M (unnormalized exp2 scores)
  //         RS (1MB) at 0 (xb dead during qk/pv) | part0 1M..13.6M | part1 13.6M..26.2M
  __hip_bfloat16* xb  = (__hip_bfloat16*)(ws + 0);
  __hip_bfloat16* wqb = (__hip_bfloat16*)(ws + 12582912);
  __hip_bfloat16* wkb = (__hip_bfloat16*)(ws + 12582912 + 1179648);
  __hip_bfloat16* wvb = (__hip_bfloat16*)(ws + 12582912 + 2 * 1179648);
  __hip_bfloat16* Qb  = (__hip_bfloat16*)(ws + 16121856);
  __hip_bfloat16* Kb  = (__hip_bfloat16*)(ws + 28704768);
  __hip_bfloat16* Vt  = (__hip_bfloat16*)(ws + 41287680);
  __hip_bfloat16* Pb  = (__hip_bfloat16*)(ws + 53870592);
  float* RS    = (float*)(ws + 0);
  float* part0 = (float*)(ws + 1048576);
  float* part1 = (float*)(ws + 1048576 + 12582912);

  cvt_kernel<<<2048, 256, 0, stream>>>(x, wq, wk, wv, xb, wqb, wkb, wvb);
  qkv_gemm<<<dim3(64, 6, 3), 256, 0, stream>>>(xb, wqb, wkb, wvb, Qb, Kb, Vt);
  qk_gemm<<<dim3(16, 16, 4), 256, 0, stream>>>(Qb, Kb, Pb, RS);
  pv_gemm<<<dim3(24, 6, 4), 256, 0, stream>>>(Pb, Vt, RS, (float*)d_out, part0, part1);
  combine_kernel<<<dim3(32, 4), 256, 0, stream>>>(part0, part1, RS, (float*)d_out);
}

// Round 13
// 194.314 us; speedup vs baseline: 1.1032x; 1.0602x over previous
//
#include <hip/hip_runtime.h>
#include <hip/hip_bf16.h>

typedef float f32x4 __attribute__((ext_vector_type(4)));
typedef short s16x8 __attribute__((ext_vector_type(8)));

#define B_ 4
#define S_ 2048
#define D_ 768

typedef const __attribute__((address_space(1))) char* gas_t;
typedef __attribute__((address_space(3))) char* las_t;

__device__ __forceinline__ void gload_lds16(const void* g, void* l) {
  __builtin_amdgcn_global_load_lds((gas_t)g, (las_t)l, 16, 0, 0);
}

// ---------------- f32 -> bf16 conversion ----------------
__global__ void cvt_kernel(const float* __restrict__ x,
                           const float* __restrict__ wq,
                           const float* __restrict__ wk,
                           const float* __restrict__ wv,
                           __hip_bfloat16* __restrict__ xb,
                           __hip_bfloat16* __restrict__ wqb,
                           __hip_bfloat16* __restrict__ wkb,
                           __hip_bfloat16* __restrict__ wvb) {
  const int NX = B_ * S_ * D_ / 4;
  const int NW = D_ * D_ / 4;
  int stride = gridDim.x * blockDim.x;
  for (int j = blockIdx.x * blockDim.x + threadIdx.x; j < NX + 3 * NW; j += stride) {
    const float4* src; __hip_bfloat16* dst; int off;
    if (j < NX)             { src = (const float4*)x;  dst = xb;  off = j; }
    else if (j < NX + NW)   { src = (const float4*)wq; dst = wqb; off = j - NX; }
    else if (j < NX + 2*NW) { src = (const float4*)wk; dst = wkb; off = j - NX - NW; }
    else                    { src = (const float4*)wv; dst = wvb; off = j - NX - 2*NW; }
    float4 v = src[off];
    dst[4*off+0] = __float2bfloat16(v.x);
    dst[4*off+1] = __float2bfloat16(v.y);
    dst[4*off+2] = __float2bfloat16(v.z);
    dst[4*off+3] = __float2bfloat16(v.w);
  }
}

// ---- 128-row staging, source pre-swizzled (rule #21) ----
__device__ __forceinline__ void stage_tile64(const __hip_bfloat16* __restrict__ base,
                                             size_t stride, int r0, int k0,
                                             char* lds, int w, int l) {
#pragma unroll
  for (int it = 0; it < 4; ++it) {
    int ra = it * 32 + w * 8 + (l >> 3);
    int slot = (l & 7) ^ ((l >> 3) & 7);
    gload_lds16(base + (size_t)(r0 + ra) * stride + k0 + slot * 8,
                lds + it * 4096 + w * 1024);
  }
}

// swizzled fragment read: element index for logical (row R, slot s)
#define SWZ_IDX(R, s) ((R) * 64 + (((s) ^ ((R) & 7)) * 8))

// ---------------- QKV projection GEMM (128², BK=64, 2-phase, swizzle) ----
__launch_bounds__(256, 2)
__global__ void qkv_gemm(const __hip_bfloat16* __restrict__ xb,
                         const __hip_bfloat16* __restrict__ wqb,
                         const __hip_bfloat16* __restrict__ wkb,
                         const __hip_bfloat16* __restrict__ wvb,
                         __hip_bfloat16* __restrict__ Qb,
                         __hip_bfloat16* __restrict__ Kb,
                         __hip_bfloat16* __restrict__ Vt) {
  __shared__ __hip_bfloat16 At[2][128 * 64];
  __shared__ __hip_bfloat16 Bt[2][128 * 64];
  const int z = blockIdx.z;
  const __hip_bfloat16* Ag;
  const __hip_bfloat16* Bg;
  int m0, n0;
  if (z == 0)      { Ag = xb;  Bg = wqb; m0 = blockIdx.x * 128; n0 = blockIdx.y * 128; }
  else if (z == 1) { Ag = xb;  Bg = wkb; m0 = blockIdx.x * 128; n0 = blockIdx.y * 128; }
  else             { Ag = wvb; Bg = xb;  m0 = blockIdx.y * 128; n0 = blockIdx.x * 128; }

  const int tid = threadIdx.x, w = tid >> 6, l = tid & 63;
  const int wr = w >> 1, wc = w & 1;
  f32x4 acc[4][4] = {};

  stage_tile64(Ag, 768, m0, 0, (char*)At[0], w, l);
  stage_tile64(Bg, 768, n0, 0, (char*)Bt[0], w, l);
  int cur = 0;
  for (int k0 = 0; k0 < 768; k0 += 64) {
    __syncthreads();
    if (k0 + 64 < 768) {
      stage_tile64(Ag, 768, m0, k0 + 64, (char*)At[cur ^ 1], w, l);
      stage_tile64(Bg, 768, n0, k0 + 64, (char*)Bt[cur ^ 1], w, l);
    }
#pragma unroll
    for (int kk = 0; kk < 2; ++kk) {
      s16x8 a[4], b[4];
      int s = kk * 4 + (l >> 4);
#pragma unroll
      for (int i = 0; i < 4; ++i) {
        int Ra = wr * 64 + i * 16 + (l & 15);
        int Rb = wc * 64 + i * 16 + (l & 15);
        a[i] = *(const s16x8*)&At[cur][SWZ_IDX(Ra, s)];
        b[i] = *(const s16x8*)&Bt[cur][SWZ_IDX(Rb, s)];
      }
#pragma unroll
      for (int i = 0; i < 4; ++i)
#pragma unroll
        for (int j = 0; j < 4; ++j)
          acc[i][j] = __builtin_amdgcn_mfma_f32_16x16x32_bf16(a[i], b[j], acc[i][j], 0, 0, 0);
    }
    cur ^= 1;
  }

  if (z < 2) {
    __hip_bfloat16* outp = (z == 0) ? Qb : Kb;
#pragma unroll
    for (int i = 0; i < 4; ++i) {
      int m = m0 + wr * 64 + i * 16 + (l >> 4) * 4;
#pragma unroll
      for (int j = 0; j < 4; ++j) {
        int n = n0 + wc * 64 + j * 16 + (l & 15);
#pragma unroll
        for (int r = 0; r < 4; ++r)
          outp[(size_t)(m + r) * 768 + n] = __float2bfloat16(acc[i][j][r]);
      }
    }
  } else {
#pragma unroll
    for (int i = 0; i < 4; ++i) {
      int dd = m0 + wr * 64 + i * 16 + (l >> 4) * 4;
#pragma unroll
      for (int j = 0; j < 4; ++j) {
        int sg = n0 + wc * 64 + j * 16 + (l & 15);
        int bb = sg >> 11, sl = sg & 2047;
#pragma unroll
        for (int r = 0; r < 4; ++r)
          Vt[(size_t)bb * D_ * S_ + (size_t)(dd + r) * S_ + sl] = __float2bfloat16(acc[i][j][r]);
      }
    }
  }
}

// ---------------- P = exp2(scale*log2e * QK^T) causal (no max-sub; |score|<=9.2) ----
// Writes P bf16 + race-free per-(block,wc) 64-col row partial sums:
// RS[b][qt][kt][wc][128]  (1 MB, in dead xb region)
__launch_bounds__(256, 2)
__global__ void qk_gemm(const __hip_bfloat16* __restrict__ Qb,
                        const __hip_bfloat16* __restrict__ Kb,
                        __hip_bfloat16* __restrict__ Pb,
                        float* __restrict__ RS) {
  __shared__ __hip_bfloat16 At[2][128 * 64];
  __shared__ __hip_bfloat16 Bt[2][128 * 64];
  const int qt = blockIdx.x, kt = blockIdx.y, b = blockIdx.z;
  if (kt > qt) return;
  const int m0 = qt * 128, n0 = kt * 128;
  const __hip_bfloat16* Ag = Qb + (size_t)b * S_ * D_;
  const __hip_bfloat16* Bg = Kb + (size_t)b * S_ * D_;
  const int tid = threadIdx.x, w = tid >> 6, l = tid & 63;
  const int wr = w >> 1, wc = w & 1;
  const float SC = 0.03608439182435161f * 1.4426950408889634f;
  f32x4 acc[4][4] = {};

  stage_tile64(Ag, D_, m0, 0, (char*)At[0], w, l);
  stage_tile64(Bg, D_, n0, 0, (char*)Bt[0], w, l);
  int cur = 0;
  for (int k0 = 0; k0 < D_; k0 += 64) {
    __syncthreads();
    if (k0 + 64 < D_) {
      stage_tile64(Ag, D_, m0, k0 + 64, (char*)At[cur ^ 1], w, l);
      stage_tile64(Bg, D_, n0, k0 + 64, (char*)Bt[cur ^ 1], w, l);
    }
#pragma unroll
    for (int kk = 0; kk < 2; ++kk) {
      s16x8 a[4], bfr[4];
      int s = kk * 4 + (l >> 4);
#pragma unroll
      for (int i = 0; i < 4; ++i) {
        int Ra = wr * 64 + i * 16 + (l & 15);
        int Rb = wc * 64 + i * 16 + (l & 15);
        a[i]   = *(const s16x8*)&At[cur][SWZ_IDX(Ra, s)];
        bfr[i] = *(const s16x8*)&Bt[cur][SWZ_IDX(Rb, s)];
      }
#pragma unroll
      for (int i = 0; i < 4; ++i)
#pragma unroll
        for (int j = 0; j < 4; ++j)
          acc[i][j] = __builtin_amdgcn_mfma_f32_16x16x32_bf16(a[i], bfr[j], acc[i][j], 0, 0, 0);
    }
    cur ^= 1;
  }

  float rps[4][4];
#pragma unroll
  for (int i = 0; i < 4; ++i)
#pragma unroll
    for (int r = 0; r < 4; ++r) rps[i][r] = 0.f;

#pragma unroll
  for (int i = 0; i < 4; ++i) {
    int m = m0 + wr * 64 + i * 16 + (l >> 4) * 4;
#pragma unroll
    for (int j = 0; j < 4; ++j) {
      int n = n0 + wc * 64 + j * 16 + (l & 15);
#pragma unroll
      for (int r = 0; r < 4; ++r) {
        float p = (n > m + r) ? 0.f : exp2f(acc[i][j][r] * SC);
        __hip_bfloat16 hp = __float2bfloat16(p);
        rps[i][r] += __bfloat162float(hp);  // sum the ROUNDED p (matches PV input)
        Pb[(size_t)(b * S_ + m + r) * S_ + n] = hp;
      }
    }
  }
  // reduce over the 16 column-lanes (low 4 lane bits)
#pragma unroll
  for (int d = 1; d < 16; d <<= 1)
#pragma unroll
    for (int i = 0; i < 4; ++i)
#pragma unroll
      for (int r = 0; r < 4; ++r) rps[i][r] += __shfl_xor(rps[i][r], d, 64);
  if ((l & 15) == 0) {
    float* slice = RS + (size_t)(((b * 16 + qt) * 16 + kt) * 2 + wc) * 128;
#pragma unroll
    for (int i = 0; i < 4; ++i) {
      int row = wr * 64 + i * 16 + (l >> 4) * 4;
#pragma unroll
      for (int r = 0; r < 4; ++r) slice[row + r] = rps[i][r];
    }
  }
}

// ---------------- O = (P V) / rowsum, full causal K per q-tile ----------------
__launch_bounds__(256, 2)
__global__ void pv_gemm(const __hip_bfloat16* __restrict__ Pb,
                        const __hip_bfloat16* __restrict__ Vt,
                        const float* __restrict__ RS,
                        float* __restrict__ out) {
  __shared__ __hip_bfloat16 At[2][128 * 64];
  __shared__ __hip_bfloat16 Bt[2][128 * 64];
  __shared__ float Ls[128];
  const int qt = 15 - (int)blockIdx.x, dt = blockIdx.y, b = blockIdx.z;
  const int m0 = qt * 128, n0 = dt * 128;
  const int khi = (qt + 1) * 128;
  const __hip_bfloat16* Ag = Pb + (size_t)b * S_ * S_;
  const __hip_bfloat16* Bg = Vt + (size_t)b * D_ * S_;
  const int tid = threadIdx.x, w = tid >> 6, l = tid & 63;
  const int wr = w >> 1, wc = w & 1;
  f32x4 acc[4][4] = {};

  if (tid < 128) {
    float s = 0.f;
    const float* base = RS + (size_t)(b * 16 + qt) * 16 * 256;
    for (int kt = 0; kt <= qt; ++kt)
      s += base[kt * 256 + tid] + base[kt * 256 + 128 + tid];
    Ls[tid] = 1.0f / s;
  }

  stage_tile64(Ag, S_, m0, 0, (char*)At[0], w, l);
  stage_tile64(Bg, S_, n0, 0, (char*)Bt[0], w, l);
  int cur = 0;
  for (int k0 = 0; k0 < khi; k0 += 64) {
    __syncthreads();
    if (k0 + 64 < khi) {
      stage_tile64(Ag, S_, m0, k0 + 64, (char*)At[cur ^ 1], w, l);
      stage_tile64(Bg, S_, n0, k0 + 64, (char*)Bt[cur ^ 1], w, l);
    }
#pragma unroll
    for (int kk = 0; kk < 2; ++kk) {
      s16x8 a[4], bfr[4];
      int s = kk * 4 + (l >> 4);
#pragma unroll
      for (int i = 0; i < 4; ++i) {
        int Ra = wr * 64 + i * 16 + (l & 15);
        int Rb = wc * 64 + i * 16 + (l & 15);
        a[i]   = *(const s16x8*)&At[cur][SWZ_IDX(Ra, s)];
        bfr[i] = *(const s16x8*)&Bt[cur][SWZ_IDX(Rb, s)];
      }
#pragma unroll
      for (int i = 0; i < 4; ++i)
#pragma unroll
        for (int j = 0; j < 4; ++j)
          acc[i][j] = __builtin_amdgcn_mfma_f32_16x16x32_bf16(a[i], bfr[j], acc[i][j], 0, 0, 0);
    }
    cur ^= 1;
  }

#pragma unroll
  for (int i = 0; i < 4; ++i) {
    int lr = wr * 64 + i * 16 + (l >> 4) * 4;
    int m = m0 + lr;
#pragma unroll
    for (int j = 0; j < 4; ++j) {
      int n = n0 + wc * 64 + j * 16 + (l & 15);
#pragma unroll
      for (int r = 0; r < 4; ++r)
        out[(size_t)(b * S_ + m + r) * D_ + n] = acc[i][j][r] * Ls[lr + r];
    }
  }
}

extern "C" void kernel_launch(void* const* d_in, const int* in_sizes, int n_in,
                              void* d_out, int out_size, void* d_ws, size_t ws_size,
                              hipStream_t stream) {
  const float* x  = (const float*)d_in[0];
  const float* wq = (const float*)d_in[1];
  const float* wk = (const float*)d_in[2];
  const float* wv = (const float*)d_in[3];
  char* ws = (char*)d_ws;
  // layout: xb 0..12.58M | w* ..16.12M | Qb ..28.70M | Kb ..41.29M | Vt ..53.87M
  //         Pb 53.87M..87.43M (unnormalized exp2 scores)
  //         RS (1MB) at 0 (xb dead during qk/pv)
  __hip_bfloat16* xb  = (__hip_bfloat16*)(ws + 0);
  __hip_bfloat16* wqb = (__hip_bfloat16*)(ws + 12582912);
  __hip_bfloat16* wkb = (__hip_bfloat16*)(ws + 12582912 + 1179648);
  __hip_bfloat16* wvb = (__hip_bfloat16*)(ws + 12582912 + 2 * 1179648);
  __hip_bfloat16* Qb  = (__hip_bfloat16*)(ws + 16121856);
  __hip_bfloat16* Kb  = (__hip_bfloat16*)(ws + 28704768);
  __hip_bfloat16* Vt  = (__hip_bfloat16*)(ws + 41287680);
  __hip_bfloat16* Pb  = (__hip_bfloat16*)(ws + 53870592);
  float* RS = (float*)(ws + 0);

  cvt_kernel<<<2048, 256, 0, stream>>>(x, wq, wk, wv, xb, wqb, wkb, wvb);
  qkv_gemm<<<dim3(64, 6, 3), 256, 0, stream>>>(xb, wqb, wkb, wvb, Qb, Kb, Vt);
  qk_gemm<<<dim3(16, 16, 4), 256, 0, stream>>>(Qb, Kb, Pb, RS);
  pv_gemm<<<dim3(16, 6, 4), 256, 0, stream>>>(Pb, Vt, RS, (float*)d_out);
}